// Round 4
// baseline (372.397 us; speedup 1.0000x reference)
//
#include <hip/hip_runtime.h>
#include <hip/hip_bf16.h>
#include <stdint.h>

typedef __hip_bfloat16 bf16;
typedef __attribute__((ext_vector_type(8))) short short8;   // 8 x bf16 = 16B
typedef __attribute__((ext_vector_type(4))) short short4v;  // 8B
typedef __attribute__((ext_vector_type(4))) float float4v;

#define MFMA16(a, b, c) __builtin_amdgcn_mfma_f32_16x16x32_bf16((a), (b), (c), 0, 0, 0)

static __device__ inline short f2bf(float f) {
    bf16 h = __float2bfloat16(f);
    return *reinterpret_cast<short*>(&h);
}

// =====================================================================
// Dtype sniffer: flag=1 means "inputs are float32" (proved true in R3,
// kept so the kernel is robust to either dtype).
// =====================================================================
__global__ void sniff_dtype(const unsigned short* __restrict__ x, int* __restrict__ flag) {
    if (threadIdx.x == 0 && blockIdx.x == 0) {
        int bad = 0;
        for (int i = 0; i < 64; ++i) {
            const unsigned e = (x[i] >> 7) & 0xFF;
            if (!(e == 0 || (e >= 0x66 && e <= 0x8A))) bad++;
        }
        flag[0] = (bad > 0) ? 1 : 0;
    }
}

// =====================================================================
// GEMM: C[M][N] = X[M][K] @ W[N][K]^T + bias[N]
// xf: X dtype override (-1 = follow flag, 0 = force bf16, 1 = force f32).
// W/bias dtype and mode-0 output dtype follow flag.
// mode 0: store C to Cout. mode 1: QKV scatter (QK row-major bf16 +
// V transposed into Vt[h][d][tok] bf16).
// 128x128 tile, BK=32, 4 waves (2x2 of 64x64), 16x16x32 bf16 MFMA.
// LDS rows padded 32->40 elems: 2-way bank aliasing only (free).
// =====================================================================
__global__ __launch_bounds__(256) void gemm_xwt(
    const void* __restrict__ X, const void* __restrict__ W,
    const void* __restrict__ bias,
    void* __restrict__ Cout,
    bf16* __restrict__ QK, bf16* __restrict__ Vt,
    const int* __restrict__ flag,
    int M, int N, int K, int mode, int xf)
{
    __shared__ __align__(16) bf16 As[128 * 40];
    __shared__ __align__(16) bf16 Bs[128 * 40];

    const bool isf  = (*flag != 0);              // weights/bias/out dtype
    const bool isfx = (xf < 0) ? isf : (xf != 0); // X dtype

    const int tid  = threadIdx.x;
    const int wave = tid >> 6;
    const int lane = tid & 63;
    const int quad = lane >> 4;
    const int l16  = lane & 15;
    const int m0 = blockIdx.x * 128;
    const int n0 = blockIdx.y * 128;
    const int wm = (wave >> 1) * 64;
    const int wn = (wave & 1) * 64;

    float4v acc[4][4];
    const float4v zf = {0.f, 0.f, 0.f, 0.f};
#pragma unroll
    for (int i = 0; i < 4; ++i)
#pragma unroll
        for (int j = 0; j < 4; ++j) acc[i][j] = zf;

    for (int k0 = 0; k0 < K; k0 += 32) {
        __syncthreads();
#pragma unroll
        for (int ii = 0; ii < 2; ++ii) {
            const int c  = tid + ii * 256;
            const int r  = c >> 2;
            const int cc = c & 3;
            short8 va, vb;
            if (isfx) {
                const float* xs = (const float*)X + (size_t)(m0 + r) * K + k0 + cc * 8;
                float4v a0 = *(const float4v*)xs, a1 = *(const float4v*)(xs + 4);
#pragma unroll
                for (int q = 0; q < 4; ++q) { va[q] = f2bf(a0[q]); va[q + 4] = f2bf(a1[q]); }
            } else {
                va = *(const short8*)((const bf16*)X + (size_t)(m0 + r) * K + k0 + cc * 8);
            }
            if (isf) {
                const float* wsrc = (const float*)W + (size_t)(n0 + r) * K + k0 + cc * 8;
                float4v b0 = *(const float4v*)wsrc, b1 = *(const float4v*)(wsrc + 4);
#pragma unroll
                for (int q = 0; q < 4; ++q) { vb[q] = f2bf(b0[q]); vb[q + 4] = f2bf(b1[q]); }
            } else {
                vb = *(const short8*)((const bf16*)W + (size_t)(n0 + r) * K + k0 + cc * 8);
            }
            *(short8*)&As[r * 40 + cc * 8] = va;
            *(short8*)&Bs[r * 40 + cc * 8] = vb;
        }
        __syncthreads();

        short8 af[4], bfr[4];
#pragma unroll
        for (int i = 0; i < 4; ++i)
            af[i] = *(const short8*)&As[(wm + i * 16 + l16) * 40 + quad * 8];
#pragma unroll
        for (int j = 0; j < 4; ++j)
            bfr[j] = *(const short8*)&Bs[(wn + j * 16 + l16) * 40 + quad * 8];
#pragma unroll
        for (int i = 0; i < 4; ++i)
#pragma unroll
            for (int j = 0; j < 4; ++j)
                acc[i][j] = MFMA16(af[i], bfr[j], acc[i][j]);
    }

    // epilogue: C/D layout col=lane&15, row=quad*4+reg
#pragma unroll
    for (int j = 0; j < 4; ++j) {
        const int col = n0 + wn + j * 16 + l16;
        const float bb = isf ? ((const float*)bias)[col]
                             : __bfloat162float(((const bf16*)bias)[col]);
#pragma unroll
        for (int i = 0; i < 4; ++i) {
#pragma unroll
            for (int r = 0; r < 4; ++r) {
                const int row = m0 + wm + i * 16 + quad * 4 + r;
                const float val = acc[i][j][r] + bb;
                if (mode == 0) {
                    if (isf) ((float*)Cout)[(size_t)row * N + col] = val;
                    else     ((bf16*)Cout)[(size_t)row * N + col] = __float2bfloat16(val);
                } else {
                    const bf16 bv = __float2bfloat16(val);
                    if (col < 2304) {
                        QK[(size_t)row * 2304 + col] = bv;
                    } else {
                        const int c2 = col - 2304;
                        const int hh = c2 / 72;
                        const int dd = c2 - hh * 72;
                        Vt[((size_t)hh * 80 + dd) * 4096 + row] = bv;
                    }
                }
            }
        }
    }
}

// =====================================================================
// Varlen flash attention (ws buffers only: always bf16).
// Grid: (qblock<=72, head=16). Block 256 = 4 waves.
// =====================================================================
__global__ __launch_bounds__(256) void attn_varlen(
    const bf16* __restrict__ QK, const bf16* __restrict__ Vt,
    const int* __restrict__ cu, bf16* __restrict__ AO)
{
    const float scale = 0.11785113019775793f;  // 72^-0.5
    __shared__ __align__(16) bf16 Qs[64 * 104];
    __shared__ __align__(16) bf16 Ks[64 * 104];
    __shared__ __align__(16) bf16 Vs[80 * 72];
    __shared__ __align__(16) bf16 Ps[4][16 * 72];

    const int tid  = threadIdx.x;
    const int wave = tid >> 6;
    const int lane = tid & 63;
    const int quad = lane >> 4;
    const int l16  = lane & 15;
    const int h  = blockIdx.y;
    const int qb = blockIdx.x;

    int seq_end = 0, q0 = -1, accb = 0, seq_start = 0;
    for (int i = 0; i < 8; ++i) {
        const int st = cu[i], en = cu[i + 1];
        const int nb = (en - st + 63) >> 6;
        if (q0 < 0 && qb < accb + nb) {
            seq_start = st; seq_end = en; q0 = st + (qb - accb) * 64;
        }
        accb += nb;
    }
    if (q0 < 0) return;

    for (int c = tid; c < 64 * 13; c += 256) {
        const int r = c / 13, cc = c - r * 13;
        short8 v = {0, 0, 0, 0, 0, 0, 0, 0};
        if (cc < 9) {
            int t = q0 + r; if (t > 4095) t = 4095;
            v = *(const short8*)&QK[(size_t)t * 2304 + h * 72 + cc * 8];
        }
        *(short8*)&Qs[r * 104 + cc * 8] = v;
    }
    __syncthreads();

    short8 aq[3];
#pragma unroll
    for (int kk = 0; kk < 3; ++kk)
        aq[kk] = *(const short8*)&Qs[(wave * 16 + l16) * 104 + kk * 32 + quad * 8];

    const float4v zf = {0.f, 0.f, 0.f, 0.f};
    float4v oacc[5];
#pragma unroll
    for (int d = 0; d < 5; ++d) oacc[d] = zf;
    float m_i[4], l_i[4];
#pragma unroll
    for (int r = 0; r < 4; ++r) { m_i[r] = -1.0e30f; l_i[r] = 0.f; }

    for (int kv0 = seq_start; kv0 < seq_end; kv0 += 64) {
        __syncthreads();
        for (int c = tid; c < 64 * 13; c += 256) {
            const int r = c / 13, cc = c - r * 13;
            short8 v = {0, 0, 0, 0, 0, 0, 0, 0};
            if (cc < 9) {
                int t = kv0 + r; if (t > 4095) t = 4095;
                v = *(const short8*)&QK[(size_t)t * 2304 + 1152 + h * 72 + cc * 8];
            }
            *(short8*)&Ks[r * 104 + cc * 8] = v;
        }
        for (int c = tid; c < 80 * 8; c += 256) {
            const int d = c >> 3, cc = c & 7;
            short4v v0 = {0, 0, 0, 0}, v1 = {0, 0, 0, 0};
            if (d < 72) {
                int tb = kv0 + cc * 8; if (tb > 4088) tb = 4088;
                const bf16* src = &Vt[((size_t)h * 80 + d) * 4096 + tb];
                v0 = *(const short4v*)src;
                v1 = *(const short4v*)(src + 4);
            }
            short4v* dst = (short4v*)&Vs[d * 72 + cc * 8];
            dst[0] = v0; dst[1] = v1;
        }
        __syncthreads();

        float4v sc[4];
#pragma unroll
        for (int nt = 0; nt < 4; ++nt) {
            float4v s = zf;
#pragma unroll
            for (int kk = 0; kk < 3; ++kk) {
                short8 bk = *(const short8*)&Ks[(nt * 16 + l16) * 104 + kk * 32 + quad * 8];
                s = MFMA16(aq[kk], bk, s);
            }
            sc[nt] = s;
        }
#pragma unroll
        for (int nt = 0; nt < 4; ++nt) {
            const int kv = kv0 + nt * 16 + l16;
            const bool ok = kv < seq_end;
#pragma unroll
            for (int r = 0; r < 4; ++r)
                sc[nt][r] = ok ? sc[nt][r] * scale : -1.0e30f;
        }
        float mnew[4], alpha[4];
#pragma unroll
        for (int r = 0; r < 4; ++r) {
            float rm = fmaxf(fmaxf(sc[0][r], sc[1][r]), fmaxf(sc[2][r], sc[3][r]));
            rm = fmaxf(rm, __shfl_xor(rm, 1));
            rm = fmaxf(rm, __shfl_xor(rm, 2));
            rm = fmaxf(rm, __shfl_xor(rm, 4));
            rm = fmaxf(rm, __shfl_xor(rm, 8));
            mnew[r]  = fmaxf(m_i[r], rm);
            alpha[r] = __expf(m_i[r] - mnew[r]);
            m_i[r]   = mnew[r];
        }
        float rs[4] = {0.f, 0.f, 0.f, 0.f};
#pragma unroll
        for (int nt = 0; nt < 4; ++nt)
#pragma unroll
            for (int r = 0; r < 4; ++r) {
                const float p = __expf(sc[nt][r] - mnew[r]);
                sc[nt][r] = p;
                rs[r] += p;
            }
#pragma unroll
        for (int r = 0; r < 4; ++r) {
            rs[r] += __shfl_xor(rs[r], 1);
            rs[r] += __shfl_xor(rs[r], 2);
            rs[r] += __shfl_xor(rs[r], 4);
            rs[r] += __shfl_xor(rs[r], 8);
            l_i[r] = l_i[r] * alpha[r] + rs[r];
        }
#pragma unroll
        for (int d = 0; d < 5; ++d)
#pragma unroll
            for (int r = 0; r < 4; ++r) oacc[d][r] *= alpha[r];

#pragma unroll
        for (int nt = 0; nt < 4; ++nt)
#pragma unroll
            for (int r = 0; r < 4; ++r)
                Ps[wave][(quad * 4 + r) * 72 + nt * 16 + l16] = __float2bfloat16(sc[nt][r]);
        __syncthreads();

        const short8 ap0 = *(const short8*)&Ps[wave][l16 * 72 + quad * 8];
        const short8 ap1 = *(const short8*)&Ps[wave][l16 * 72 + 32 + quad * 8];
#pragma unroll
        for (int d = 0; d < 5; ++d) {
            short8 bv0 = *(const short8*)&Vs[(d * 16 + l16) * 72 + quad * 8];
            short8 bv1 = *(const short8*)&Vs[(d * 16 + l16) * 72 + 32 + quad * 8];
            oacc[d] = MFMA16(ap0, bv0, oacc[d]);
            oacc[d] = MFMA16(ap1, bv1, oacc[d]);
        }
    }

#pragma unroll
    for (int r = 0; r < 4; ++r) {
        const int qrow = q0 + wave * 16 + quad * 4 + r;
        if (qrow < seq_end) {
            const float inv = (l_i[r] > 0.f) ? (1.0f / l_i[r]) : 0.f;
#pragma unroll
            for (int d = 0; d < 5; ++d) {
                const int dim = d * 16 + l16;
                if (dim < 72)
                    AO[(size_t)qrow * 1152 + h * 72 + dim] =
                        __float2bfloat16(oacc[d][r] * inv);
            }
        }
    }
}

extern "C" void kernel_launch(void* const* d_in, const int* in_sizes, int n_in,
                              void* d_out, int out_size, void* d_ws, size_t ws_size,
                              hipStream_t stream)
{
    const void* Xh   = d_in[0];  // [4096][1152]  f32 (sniffed)
    const void* Wqkv = d_in[1];  // [3456][1152]
    const void* Bqkv = d_in[2];  // [3456]
    const void* Wout = d_in[3];  // [1152][1152]
    const void* Bout = d_in[4];  // [1152]
    const int*  cu   = (const int*)d_in[5];   // [9]

    const size_t QK_BYTES = (size_t)4096 * 2304 * 2;
    const size_t VT_BYTES = (size_t)16 * 80 * 4096 * 2;
    const size_t AO_BYTES = (size_t)4096 * 1152 * 2;
    const size_t WS_USED  = QK_BYTES + VT_BYTES + AO_BYTES;  // ~38.8 MB

    char* ws = (char*)d_ws;
    bf16* QK = (bf16*)ws;
    bf16* Vt = (bf16*)(ws + QK_BYTES);
    bf16* AO = (bf16*)(ws + QK_BYTES + VT_BYTES);
    int* flag = (int*)(ws + WS_USED);

    hipMemsetAsync(d_ws, 0, WS_USED + 64, stream);

    dim3 blk(256);
    sniff_dtype<<<1, 64, 0, stream>>>((const unsigned short*)Xh, flag);
    // GEMM1: X = hidden_states, dtype per flag (xf=-1)
    gemm_xwt<<<dim3(32, 27), blk, 0, stream>>>(Xh, Wqkv, Bqkv, nullptr, QK, Vt, flag,
                                               4096, 3456, 1152, 1, -1);
    attn_varlen<<<dim3(72, 16), blk, 0, stream>>>(QK, Vt, cu, AO);
    // GEMM2: X = AO which is ALWAYS bf16 (xf=0) — this was the R3 bug
    gemm_xwt<<<dim3(32, 9), blk, 0, stream>>>(AO, Wout, Bout, d_out, nullptr, nullptr, flag,
                                              4096, 1152, 1152, 0, 0);
}

// Round 5
// 283.505 us; speedup vs baseline: 1.3135x; 1.3135x over previous
//
#include <hip/hip_runtime.h>
#include <hip/hip_bf16.h>
#include <stdint.h>

typedef __hip_bfloat16 bf16;
typedef __attribute__((ext_vector_type(8))) short short8;   // 8 x bf16 = 16B
typedef __attribute__((ext_vector_type(4))) short short4v;  // 8B
typedef __attribute__((ext_vector_type(4))) float float4v;

#define MFMA16(a, b, c) __builtin_amdgcn_mfma_f32_16x16x32_bf16((a), (b), (c), 0, 0, 0)

static __device__ __forceinline__ short f2bf(float f) {
    bf16 h = __float2bfloat16(f);
    return *reinterpret_cast<short*>(&h);
}

// async global->LDS, 16B per lane; dest = lds_base + lane*16 (wave-uniform base)
static __device__ __forceinline__ void gl2lds16(const void* g, void* l) {
    __builtin_amdgcn_global_load_lds(
        (const __attribute__((address_space(1))) void*)g,
        (__attribute__((address_space(3))) void*)l, 16, 0, 0);
}

// =====================================================================
// f32 -> bf16 elementwise convert (n multiple of 8)
// =====================================================================
__global__ __launch_bounds__(256) void cvt_f32_bf16(
    const float* __restrict__ in, bf16* __restrict__ out, int n)
{
    const int i = (blockIdx.x * 256 + threadIdx.x) * 8;
    if (i < n) {
        const float4v a = *(const float4v*)(in + i);
        const float4v b = *(const float4v*)(in + i + 4);
        short8 v;
#pragma unroll
        for (int q = 0; q < 4; ++q) { v[q] = f2bf(a[q]); v[q + 4] = f2bf(b[q]); }
        *(short8*)(out + i) = v;
    }
}

// =====================================================================
// GEMM: C[M][N] = X[M][K] @ W[N][K]^T + bias[N]; X,W bf16, bias f32.
// mode 0: store C f32 to Cout (stride N)
// mode 1: QKV scatter: col<2304 -> QK bf16 row-major; col>=2304 -> Vt bf16
//         transposed [h][d][tok].
// 128x128 tile, BK=32, 4 waves (2x2 of 64x64), 16x16x32 bf16 MFMA.
// Staging: global_load_lds 16B/lane into unpadded [128][32] LDS tiles;
// 16B-chunk index XOR-swizzled by (row>>1)&3 (applied to the GLOBAL source
// chunk, since the LDS dest is forced lane-contiguous) so fragment
// ds_read_b128s are <=2-way bank-aliased (free).
// =====================================================================
__global__ __launch_bounds__(256) void gemm_xwt(
    const bf16* __restrict__ X, const bf16* __restrict__ W,
    const float* __restrict__ bias,
    float* __restrict__ Cout,
    bf16* __restrict__ QK, bf16* __restrict__ Vt,
    int M, int N, int K, int mode)
{
    __shared__ __align__(16) bf16 As[128 * 32];
    __shared__ __align__(16) bf16 Bs[128 * 32];

    const int tid  = threadIdx.x;
    const int wave = tid >> 6;
    const int lane = tid & 63;
    const int quad = lane >> 4;
    const int l16  = lane & 15;
    const int m0 = blockIdx.x * 128;
    const int n0 = blockIdx.y * 128;
    const int wm = (wave >> 1) * 64;
    const int wn = (wave & 1) * 64;

    // staging lane roles: 4 lanes per row (16B chunks), 16 rows per issue
    const int lrow   = lane >> 2;   // 0..15
    const int lchunk = lane & 3;    // 16B chunk within a 64B row

    float4v acc[4][4];
    const float4v zf = {0.f, 0.f, 0.f, 0.f};
#pragma unroll
    for (int i = 0; i < 4; ++i)
#pragma unroll
        for (int j = 0; j < 4; ++j) acc[i][j] = zf;

    for (int k0 = 0; k0 < K; k0 += 32) {
        __syncthreads();   // prior iter's LDS reads complete
        // wave w stages rows [w*32, w*32+32) of both tiles: 2 issues each
#pragma unroll
        for (int ii = 0; ii < 2; ++ii) {
            const int rbase = wave * 32 + ii * 16;
            const int r  = rbase + lrow;
            const int sc = lchunk ^ ((r >> 1) & 3);   // swizzled source chunk
            gl2lds16(&X[(size_t)(m0 + r) * K + k0 + sc * 8], &As[rbase * 32]);
            gl2lds16(&W[(size_t)(n0 + r) * K + k0 + sc * 8], &Bs[rbase * 32]);
        }
        __syncthreads();   // drains vmcnt -> staged data visible

        short8 af[4], bfr[4];
#pragma unroll
        for (int i = 0; i < 4; ++i) {
            const int r = wm + i * 16 + l16;
            af[i] = *(const short8*)&As[r * 32 + (quad ^ ((r >> 1) & 3)) * 8];
        }
#pragma unroll
        for (int j = 0; j < 4; ++j) {
            const int r = wn + j * 16 + l16;
            bfr[j] = *(const short8*)&Bs[r * 32 + (quad ^ ((r >> 1) & 3)) * 8];
        }
#pragma unroll
        for (int i = 0; i < 4; ++i)
#pragma unroll
            for (int j = 0; j < 4; ++j)
                acc[i][j] = MFMA16(af[i], bfr[j], acc[i][j]);
    }

    // epilogue: C/D layout col=lane&15, row=quad*4+reg
#pragma unroll
    for (int j = 0; j < 4; ++j) {
        const int col = n0 + wn + j * 16 + l16;
        const float bb = bias[col];
#pragma unroll
        for (int i = 0; i < 4; ++i) {
#pragma unroll
            for (int r = 0; r < 4; ++r) {
                const int row = m0 + wm + i * 16 + quad * 4 + r;
                const float val = acc[i][j][r] + bb;
                if (mode == 0) {
                    Cout[(size_t)row * N + col] = val;
                } else {
                    const bf16 bv = __float2bfloat16(val);
                    if (col < 2304) {
                        QK[(size_t)row * 2304 + col] = bv;
                    } else {
                        const int c2 = col - 2304;
                        const int hh = c2 / 72;
                        const int dd = c2 - hh * 72;
                        Vt[((size_t)hh * 72 + dd) * 4096 + row] = bv;
                    }
                }
            }
        }
    }
}

// =====================================================================
// Varlen flash attention (ws buffers, all bf16).
// Grid: (qblock<=72, head=16). Block 256 = 4 waves.
// =====================================================================
__global__ __launch_bounds__(256) void attn_varlen(
    const bf16* __restrict__ QK, const bf16* __restrict__ Vt,
    const int* __restrict__ cu, bf16* __restrict__ AO)
{
    const float scale = 0.11785113019775793f;  // 72^-0.5
    __shared__ __align__(16) bf16 Qs[64 * 104];
    __shared__ __align__(16) bf16 Ks[64 * 104];
    __shared__ __align__(16) bf16 Vs[80 * 72];
    __shared__ __align__(16) bf16 Ps[4][16 * 72];

    const int tid  = threadIdx.x;
    const int wave = tid >> 6;
    const int lane = tid & 63;
    const int quad = lane >> 4;
    const int l16  = lane & 15;
    const int h  = blockIdx.y;
    const int qb = blockIdx.x;

    int seq_end = 0, q0 = -1, accb = 0, seq_start = 0;
    for (int i = 0; i < 8; ++i) {
        const int st = cu[i], en = cu[i + 1];
        const int nb = (en - st + 63) >> 6;
        if (q0 < 0 && qb < accb + nb) {
            seq_start = st; seq_end = en; q0 = st + (qb - accb) * 64;
        }
        accb += nb;
    }
    if (q0 < 0) return;

    for (int c = tid; c < 64 * 13; c += 256) {
        const int r = c / 13, cc = c - r * 13;
        short8 v = {0, 0, 0, 0, 0, 0, 0, 0};
        if (cc < 9) {
            int t = q0 + r; if (t > 4095) t = 4095;
            v = *(const short8*)&QK[(size_t)t * 2304 + h * 72 + cc * 8];
        }
        *(short8*)&Qs[r * 104 + cc * 8] = v;
    }
    __syncthreads();

    short8 aq[3];
#pragma unroll
    for (int kk = 0; kk < 3; ++kk)
        aq[kk] = *(const short8*)&Qs[(wave * 16 + l16) * 104 + kk * 32 + quad * 8];

    const float4v zf = {0.f, 0.f, 0.f, 0.f};
    float4v oacc[5];
#pragma unroll
    for (int d = 0; d < 5; ++d) oacc[d] = zf;
    float m_i[4], l_i[4];
#pragma unroll
    for (int r = 0; r < 4; ++r) { m_i[r] = -1.0e30f; l_i[r] = 0.f; }

    for (int kv0 = seq_start; kv0 < seq_end; kv0 += 64) {
        __syncthreads();
        for (int c = tid; c < 64 * 13; c += 256) {
            const int r = c / 13, cc = c - r * 13;
            short8 v = {0, 0, 0, 0, 0, 0, 0, 0};
            if (cc < 9) {
                int t = kv0 + r; if (t > 4095) t = 4095;
                v = *(const short8*)&QK[(size_t)t * 2304 + 1152 + h * 72 + cc * 8];
            }
            *(short8*)&Ks[r * 104 + cc * 8] = v;
        }
        for (int c = tid; c < 80 * 8; c += 256) {
            const int d = c >> 3, cc = c & 7;
            short4v v0 = {0, 0, 0, 0}, v1 = {0, 0, 0, 0};
            if (d < 72) {
                int tb = kv0 + cc * 8; if (tb > 4088) tb = 4088;
                const bf16* src = &Vt[((size_t)h * 72 + d) * 4096 + tb];
                v0 = *(const short4v*)src;
                v1 = *(const short4v*)(src + 4);
            }
            short4v* dst = (short4v*)&Vs[d * 72 + cc * 8];
            dst[0] = v0; dst[1] = v1;
        }
        __syncthreads();

        float4v sc[4];
#pragma unroll
        for (int nt = 0; nt < 4; ++nt) {
            float4v s = zf;
#pragma unroll
            for (int kk = 0; kk < 3; ++kk) {
                short8 bk = *(const short8*)&Ks[(nt * 16 + l16) * 104 + kk * 32 + quad * 8];
                s = MFMA16(aq[kk], bk, s);
            }
            sc[nt] = s;
        }
#pragma unroll
        for (int nt = 0; nt < 4; ++nt) {
            const int kv = kv0 + nt * 16 + l16;
            const bool ok = kv < seq_end;
#pragma unroll
            for (int r = 0; r < 4; ++r)
                sc[nt][r] = ok ? sc[nt][r] * scale : -1.0e30f;
        }
        float mnew[4], alpha[4];
#pragma unroll
        for (int r = 0; r < 4; ++r) {
            float rm = fmaxf(fmaxf(sc[0][r], sc[1][r]), fmaxf(sc[2][r], sc[3][r]));
            rm = fmaxf(rm, __shfl_xor(rm, 1));
            rm = fmaxf(rm, __shfl_xor(rm, 2));
            rm = fmaxf(rm, __shfl_xor(rm, 4));
            rm = fmaxf(rm, __shfl_xor(rm, 8));
            mnew[r]  = fmaxf(m_i[r], rm);
            alpha[r] = __expf(m_i[r] - mnew[r]);
            m_i[r]   = mnew[r];
        }
        float rs[4] = {0.f, 0.f, 0.f, 0.f};
#pragma unroll
        for (int nt = 0; nt < 4; ++nt)
#pragma unroll
            for (int r = 0; r < 4; ++r) {
                const float p = __expf(sc[nt][r] - mnew[r]);
                sc[nt][r] = p;
                rs[r] += p;
            }
#pragma unroll
        for (int r = 0; r < 4; ++r) {
            rs[r] += __shfl_xor(rs[r], 1);
            rs[r] += __shfl_xor(rs[r], 2);
            rs[r] += __shfl_xor(rs[r], 4);
            rs[r] += __shfl_xor(rs[r], 8);
            l_i[r] = l_i[r] * alpha[r] + rs[r];
        }
#pragma unroll
        for (int d = 0; d < 5; ++d)
#pragma unroll
            for (int r = 0; r < 4; ++r) oacc[d][r] *= alpha[r];

#pragma unroll
        for (int nt = 0; nt < 4; ++nt)
#pragma unroll
            for (int r = 0; r < 4; ++r)
                Ps[wave][(quad * 4 + r) * 72 + nt * 16 + l16] = __float2bfloat16(sc[nt][r]);
        __syncthreads();

        const short8 ap0 = *(const short8*)&Ps[wave][l16 * 72 + quad * 8];
        const short8 ap1 = *(const short8*)&Ps[wave][l16 * 72 + 32 + quad * 8];
#pragma unroll
        for (int d = 0; d < 5; ++d) {
            short8 bv0 = *(const short8*)&Vs[(d * 16 + l16) * 72 + quad * 8];
            short8 bv1 = *(const short8*)&Vs[(d * 16 + l16) * 72 + 32 + quad * 8];
            oacc[d] = MFMA16(ap0, bv0, oacc[d]);
            oacc[d] = MFMA16(ap1, bv1, oacc[d]);
        }
    }

#pragma unroll
    for (int r = 0; r < 4; ++r) {
        const int qrow = q0 + wave * 16 + quad * 4 + r;
        if (qrow < seq_end) {
            const float inv = (l_i[r] > 0.f) ? (1.0f / l_i[r]) : 0.f;
#pragma unroll
            for (int d = 0; d < 5; ++d) {
                const int dim = d * 16 + l16;
                if (dim < 72)
                    AO[(size_t)qrow * 1152 + h * 72 + dim] =
                        __float2bfloat16(oacc[d][r] * inv);
            }
        }
    }
}

extern "C" void kernel_launch(void* const* d_in, const int* in_sizes, int n_in,
                              void* d_out, int out_size, void* d_ws, size_t ws_size,
                              hipStream_t stream)
{
    const float* Xf   = (const float*)d_in[0];  // [4096][1152]
    const float* Wqkv = (const float*)d_in[1];  // [3456][1152]
    const float* Bqkv = (const float*)d_in[2];  // [3456]
    const float* Wout = (const float*)d_in[3];  // [1152][1152]
    const float* Bout = (const float*)d_in[4];  // [1152]
    const int*   cu   = (const int*)d_in[5];    // [9]

    const size_t X16_B  = (size_t)4096 * 1152 * 2;   //  9.44 MB
    const size_t WQ16_B = (size_t)3456 * 1152 * 2;   //  7.96 MB
    const size_t WO16_B = (size_t)1152 * 1152 * 2;   //  2.65 MB
    const size_t QK_B   = (size_t)4096 * 2304 * 2;   // 18.87 MB
    const size_t VT_B   = (size_t)16 * 72 * 4096 * 2;//  9.44 MB
    // AO: 9.44 MB.  Total ~57.2 MB.

    char* ws = (char*)d_ws;
    bf16* X16  = (bf16*)ws;
    bf16* WQ16 = (bf16*)(ws + X16_B);
    bf16* WO16 = (bf16*)(ws + X16_B + WQ16_B);
    bf16* QK   = (bf16*)(ws + X16_B + WQ16_B + WO16_B);
    bf16* Vt   = (bf16*)(ws + X16_B + WQ16_B + WO16_B + QK_B);
    bf16* AO   = (bf16*)(ws + X16_B + WQ16_B + WO16_B + QK_B + VT_B);
    float* Out = (float*)d_out;

    dim3 blk(256);
    // f32 -> bf16 conversions (one-shot, memory-bound)
    cvt_f32_bf16<<<dim3((4096 * 1152 / 8 + 255) / 256), blk, 0, stream>>>(Xf, X16, 4096 * 1152);
    cvt_f32_bf16<<<dim3((3456 * 1152 / 8 + 255) / 256), blk, 0, stream>>>(Wqkv, WQ16, 3456 * 1152);
    cvt_f32_bf16<<<dim3((1152 * 1152 / 8 + 255) / 256), blk, 0, stream>>>(Wout, WO16, 1152 * 1152);

    // QKV projection (scatter Q,K row-major bf16 + V transposed)
    gemm_xwt<<<dim3(32, 27), blk, 0, stream>>>(X16, WQ16, Bqkv, nullptr, QK, Vt,
                                               4096, 3456, 1152, 1);
    // varlen attention
    attn_varlen<<<dim3(72, 16), blk, 0, stream>>>(QK, Vt, cu, AO);
    // output projection (f32 store to d_out)
    gemm_xwt<<<dim3(32, 9), blk, 0, stream>>>(AO, WO16, Bout, Out, nullptr, nullptr,
                                              4096, 1152, 1152, 0);
}